// Round 4
// baseline (354.380 us; speedup 1.0000x reference)
//
#include <hip/hip_runtime.h>

typedef __attribute__((ext_vector_type(8))) __bf16 bf16x8;
typedef __attribute__((ext_vector_type(4))) __bf16 bf16x4;
typedef __attribute__((ext_vector_type(4))) float f32x4;

#define SCALE_LOG2E 0.18033688011112042f  // 0.125 * log2(e)

__device__ __forceinline__ f32x4 mfma16(bf16x8 a, bf16x8 b, f32x4 c) {
  return __builtin_amdgcn_mfma_f32_16x16x32_bf16(a, b, c, 0, 0, 0);
}

__device__ __forceinline__ void gload_lds16(const void* g, void* l) {
  __builtin_amdgcn_global_load_lds(
      (__attribute__((address_space(1))) void*)(void*)g,
      (__attribute__((address_space(3))) void*)l, 16, 0, 0);
}

// read swizzled [row][64-elem] LDS tile: logical chunk lc (0..7) of row
__device__ __forceinline__ bf16x8 ldsfrag(const __bf16* base, int row, int lc) {
  return *(const bf16x8*)(base + row * 64 + ((lc ^ (row & 7)) << 3));
}

// ---------------- cast kernels ----------------

__global__ __launch_bounds__(256) void cast_plain(const float* __restrict__ in,
                                                  __bf16* __restrict__ out) {
  size_t t = (size_t)blockIdx.x * 256 + threadIdx.x;
  const float4* p = (const float4*)(in + t * 8);
  float4 a = p[0], b = p[1];
  bf16x8 v;
  v[0] = (__bf16)a.x; v[1] = (__bf16)a.y; v[2] = (__bf16)a.z; v[3] = (__bf16)a.w;
  v[4] = (__bf16)b.x; v[5] = (__bf16)b.y; v[6] = (__bf16)b.z; v[7] = (__bf16)b.w;
  *(bf16x8*)(out + t * 8) = v;
}

__global__ __launch_bounds__(256) void cast_cat(const float* __restrict__ mem,
                                                const float* __restrict__ w,
                                                __bf16* __restrict__ out) {
  size_t t = (size_t)blockIdx.x * 256 + threadIdx.x;
  size_t o = t * 8;
  int c = (int)(o & 1023);
  int row = (int)(o >> 10);
  int tt = row & 2047;
  int b = row >> 11;
  const float* src = (tt < 1024)
      ? (mem + ((size_t)(b * 1024 + tt) * 1024 + c))
      : (w + ((size_t)(b * 1024 + (tt - 1024)) * 1024 + c));
  float4 a = ((const float4*)src)[0], d = ((const float4*)src)[1];
  bf16x8 v;
  v[0] = (__bf16)a.x; v[1] = (__bf16)a.y; v[2] = (__bf16)a.z; v[3] = (__bf16)a.w;
  v[4] = (__bf16)d.x; v[5] = (__bf16)d.y; v[6] = (__bf16)d.z; v[7] = (__bf16)d.w;
  *(bf16x8*)(out + o) = v;
}

// ---------------- GEMM: C = A(MxK) * B(NxK)^T ----------------
template <int MODE>
__global__ __launch_bounds__(256, 2) void gemm_bt(const __bf16* __restrict__ A,
                                                  const __bf16* __restrict__ B,
                                                  __bf16* __restrict__ Cb,
                                                  float* __restrict__ Cf,
                                                  const float* __restrict__ Res,
                                                  int M, int N, int K, int skipq) {
  // skip blocks computing q-columns of mem-rows (never consumed downstream)
  if (skipq && blockIdx.x < 8 && (blockIdx.y & 15) < 8) return;
  __shared__ __bf16 As[128 * 32];
  __shared__ __bf16 Bs[128 * 32];
  const int tid = threadIdx.x;
  const int wid = tid >> 6, lane = tid & 63;
  const int l15 = lane & 15, lhi = lane >> 4;
  const int wr = wid >> 1, wc = wid & 1;
  const size_t arow0 = (size_t)blockIdx.y * 128;
  const size_t brow0 = (size_t)blockIdx.x * 128;

  f32x4 acc[4][4] = {};

  const int c0 = tid, c1 = tid + 256;
  const int r0 = c0 >> 2, o0 = (c0 & 3) * 8;
  const int r1 = c1 >> 2, o1 = (c1 & 3) * 8;
  const __bf16* ga0 = A + (arow0 + r0) * K + o0;
  const __bf16* ga1 = A + (arow0 + r1) * K + o1;
  const __bf16* gb0 = B + (brow0 + r0) * K + o0;
  const __bf16* gb1 = B + (brow0 + r1) * K + o1;
  __bf16* la0 = As + wid * 512;
  __bf16* la1 = As + 2048 + wid * 512;
  __bf16* lb0 = Bs + wid * 512;
  __bf16* lb1 = Bs + 2048 + wid * 512;

  for (int k0 = 0; k0 < K; k0 += 32) {
    gload_lds16(ga0 + k0, la0);
    gload_lds16(ga1 + k0, la1);
    gload_lds16(gb0 + k0, lb0);
    gload_lds16(gb1 + k0, lb1);
    __syncthreads();
    bf16x8 af[4], bf[4];
#pragma unroll
    for (int m = 0; m < 4; ++m)
      af[m] = *(const bf16x8*)(As + (wr * 64 + m * 16 + l15) * 32 + lhi * 8);
#pragma unroll
    for (int n = 0; n < 4; ++n)
      bf[n] = *(const bf16x8*)(Bs + (wc * 64 + n * 16 + l15) * 32 + lhi * 8);
#pragma unroll
    for (int m = 0; m < 4; ++m)
#pragma unroll
      for (int n = 0; n < 4; ++n)
        acc[m][n] = mfma16(af[m], bf[n], acc[m][n]);
    __syncthreads();
  }

#pragma unroll
  for (int m = 0; m < 4; ++m)
#pragma unroll
    for (int n = 0; n < 4; ++n) {
      size_t row = arow0 + wr * 64 + m * 16 + lhi * 4;
      size_t col = brow0 + wc * 64 + n * 16 + l15;
#pragma unroll
      for (int j = 0; j < 4; ++j) {
        size_t idx = (row + j) * (size_t)N + col;
        float v = acc[m][n][j];
        if (MODE == 0) Cb[idx] = (__bf16)v;
        else Cf[idx] = v + Res[idx];
      }
    }
}

// ---------------- V transpose: vT[b][h][d][j] ----------------
__global__ __launch_bounds__(256) void vtrans_kernel(const __bf16* __restrict__ heads,
                                                     __bf16* __restrict__ vT) {
  __shared__ __bf16 T[64][66];
  const int j0 = blockIdx.x * 64;
  const int h = blockIdx.y, b = blockIdx.z;
  const int tid = threadIdx.x;
  {
    int jj = tid >> 2, dq = tid & 3;
    const __bf16* src = heads + ((size_t)(b * 2048 + j0 + jj)) * 3072 + 2048 + h * 64 + dq * 16;
    bf16x8 a = *(const bf16x8*)src;
    bf16x8 c = *(const bf16x8*)(src + 8);
#pragma unroll
    for (int e = 0; e < 8; ++e) { T[jj][dq * 16 + e] = a[e]; T[jj][dq * 16 + 8 + e] = c[e]; }
  }
  __syncthreads();
  {
    int d = tid >> 2, jq = tid & 3;
    bf16x8 o0, o1;
#pragma unroll
    for (int e = 0; e < 8; ++e) { o0[e] = T[jq * 16 + e][d]; o1[e] = T[jq * 16 + 8 + e][d]; }
    __bf16* dst = vT + ((size_t)((b * 16 + h) * 64 + d)) * 2048 + j0 + jq * 16;
    *(bf16x8*)dst = o0;
    *(bf16x8*)(dst + 8) = o1;
  }
}

// ---------------- bias-dot precomputes (scale = 0.125*log2e folded in) ----------------
__global__ __launch_bounds__(256) void ackb_kernel(const __bf16* __restrict__ heads,
                                                   const float* __restrict__ r_w_bias,
                                                   float* __restrict__ ackb) {
  int gid = blockIdx.x * 256 + threadIdx.x;  // 131072
  int j = gid & 2047, bh = gid >> 11, b = bh >> 4, h = bh & 15;
  const __bf16* kp = heads + ((size_t)(b * 2048 + j)) * 3072 + 1024 + h * 64;
  const float* bw = r_w_bias + h * 64;
  float s = 0.f;
#pragma unroll
  for (int o = 0; o < 8; ++o) {
    bf16x8 kv = *(const bf16x8*)(kp + o * 8);
#pragma unroll
    for (int e = 0; e < 8; ++e) s += (float)kv[e] * bw[o * 8 + e];
  }
  ackb[(size_t)bh * 2048 + j] = s * SCALE_LOG2E;
}

// brk[h][t] padded to 2304 per h (zeros past 2047)
__global__ __launch_bounds__(256) void brk_kernel(const __bf16* __restrict__ rk,
                                                  const float* __restrict__ r_r_bias,
                                                  float* __restrict__ brk) {
  int gid = blockIdx.x * 256 + threadIdx.x;  // 36864
  int t = gid % 2304, h = gid / 2304;
  float s = 0.f;
  if (t < 2048) {
    const __bf16* rp = rk + (size_t)t * 1024 + h * 64;
    const float* br = r_r_bias + h * 64;
#pragma unroll
    for (int o = 0; o < 8; ++o) {
      bf16x8 rv = *(const bf16x8*)(rp + o * 8);
#pragma unroll
      for (int e = 0; e < 8; ++e) s += (float)rv[e] * br[o * 8 + e];
    }
  }
  brk[(size_t)h * 2304 + t] = s * SCALE_LOG2E;
}

// ---------------- attention ----------------
// dbuf K/V staging, register-prefetched rk, exp2-domain softmax, defer-rescale
__global__ __launch_bounds__(256) void attn_kernel(
    const __bf16* __restrict__ heads, const __bf16* __restrict__ rk,
    const __bf16* __restrict__ vT, const float* __restrict__ ackb,
    const float* __restrict__ brk, __bf16* __restrict__ vec) {
  __shared__ __bf16 Ks[2 * 4096];
  __shared__ __bf16 Vt[2 * 4096];
  __shared__ __bf16 Pool[4][2112];  // per-wave: band [16][132] / P [16][72] union

  // decode: XCD = lin&7 -> heads {x, x+8}; seq sweeps bq descending (longest first)
  const int lin = blockIdx.x;
  const int seq = lin >> 3;
  const int bq = 15 - (seq >> 3);
  const int rem = seq & 7;
  const int b = rem >> 1;
  const int h = (lin & 7) + ((rem & 1) << 3);
  const int base = bq << 6;

  const int tid = threadIdx.x;
  const int wid = tid >> 6, lane = tid & 63;
  const int l15 = lane & 15, lhi = lane >> 4;
  const int i0 = base + wid * 16;

  const int srow8 = lane >> 3;
  const int sch = (lane & 7) ^ (srow8 & 7);

  // q fragments, pre-scaled by 0.125*log2e (biases folded into ackb/brk)
  bf16x8 q0, q1;
  {
    const __bf16* qp =
        heads + ((size_t)(b * 2048 + 1024 + i0 + l15)) * 3072 + h * 64 + lhi * 8;
    bf16x8 a = *(const bf16x8*)qp;
    bf16x8 c = *(const bf16x8*)(qp + 32);
#pragma unroll
    for (int e = 0; e < 8; ++e) {
      q0[e] = (__bf16)((float)a[e] * SCALE_LOG2E);
      q1[e] = (__bf16)((float)c[e] * SCALE_LOG2E);
    }
  }

  const float* ackbp = ackb + ((size_t)(b * 16 + h)) * 2048;
  const float* brkp = brk + (size_t)h * 2304;
  __bf16* BPW = Pool[wid];

  float m_run = -1e30f, l_run = 0.f;
  f32x4 accv[4] = {};

#define STAGE_KV(J0, BUF)                                                              \
  do {                                                                                 \
    const __bf16* kst = heads +                                                        \
        ((size_t)(b * 2048 + (J0) + wid * 16 + srow8)) * 3072 + 1024 + h * 64 + sch * 8; \
    gload_lds16(kst, Ks + (BUF) * 4096 + wid * 16 * 64);                               \
    gload_lds16(kst + (size_t)8 * 3072, Ks + (BUF) * 4096 + (wid * 16 + 8) * 64);      \
    const __bf16* vst = vT +                                                           \
        ((size_t)((b * 16 + h) * 64 + wid * 16 + srow8)) * 2048 + (J0) + sch * 8;      \
    gload_lds16(vst, Vt + (BUF) * 4096 + wid * 16 * 64);                               \
    gload_lds16(vst + (size_t)8 * 2048, Vt + (BUF) * 4096 + (wid * 16 + 8) * 64);      \
  } while (0)

  // prologue: stage step 0 into buf 0; prefetch rk tiles for step 0
  bf16x8 rka[5][2];
  STAGE_KV(0, 0);
  {
    const int tb0 = 1008 - i0;  // >= 0
#pragma unroll
    for (int ct = 0; ct < 5; ++ct) {
      int t = min(tb0 + ct * 16 + l15, 2047);
      const __bf16* rp = rk + (size_t)t * 1024 + h * 64 + lhi * 8;
      rka[ct][0] = *(const bf16x8*)rp;
      rka[ct][1] = *(const bf16x8*)(rp + 32);
    }
  }

  const int jmaxb = min(2048, base + 1088);
  for (int j0 = 0; j0 < jmaxb; j0 += 64) {
    const int buf = (j0 >> 6) & 1;
    __syncthreads();  // drains staged loads + rk prefetch; syncs buffer reuse
    if (j0 + 64 < jmaxb) STAGE_KV(j0 + 64, buf ^ 1);
    if (j0 >= i0 + 1040) continue;  // fully masked for this wave

    const __bf16* KsC = Ks + buf * 4096;
    const __bf16* VtC = Vt + buf * 4096;
    const int tbase = j0 + 1008 - i0;  // >= 0

    // ---- band^T[c][i]: mfma(rk, q) from registers (+brk init) ----
#pragma unroll
    for (int ct = 0; ct < 5; ++ct) {
      int cb = ct * 16 + lhi * 4;
      f32x4 init = *(const f32x4*)(brkp + tbase + cb);
      f32x4 bd = mfma16(rka[ct][1], q1, mfma16(rka[ct][0], q0, init));
      bf16x4 bv;
      bv[0] = (__bf16)bd[0]; bv[1] = (__bf16)bd[1];
      bv[2] = (__bf16)bd[2]; bv[3] = (__bf16)bd[3];
      *(bf16x4*)(BPW + l15 * 132 + cb) = bv;
    }
    // rotate overlap tile, prefetch next-step rk into registers (consumed after sync)
    rka[0][0] = rka[4][0];
    rka[0][1] = rka[4][1];
#pragma unroll
    for (int ct = 1; ct < 5; ++ct) {
      int t = min(tbase + 64 + ct * 16 + l15, 2047);
      const __bf16* rp = rk + (size_t)t * 1024 + h * 64 + lhi * 8;
      rka[ct][0] = *(const bf16x8*)rp;
      rka[ct][1] = *(const bf16x8*)(rp + 32);
    }

    // ---- AC^T: mfma(K, q), rows j, cols i=l15, init ackb[j] ----
    f32x4 st[4];
#pragma unroll
    for (int jt = 0; jt < 4; ++jt) {
      bf16x8 k0 = ldsfrag(KsC, jt * 16 + l15, lhi);
      bf16x8 k1 = ldsfrag(KsC, jt * 16 + l15, 4 + lhi);
      f32x4 init = *(const f32x4*)(ackbp + j0 + jt * 16 + lhi * 4);
      st[jt] = mfma16(k1, q1, mfma16(k0, q0, init));
    }

    // ---- assemble S^T; mask only on boundary steps (wave-uniform branch) ----
    float sv[4][4];
#pragma unroll
    for (int jt = 0; jt < 4; ++jt)
#pragma unroll
      for (int r2 = 0; r2 < 4; ++r2) {
        int jl = jt * 16 + lhi * 4 + r2;
        sv[jt][r2] = st[jt][r2] + (float)BPW[l15 * 132 + jl + 15 - l15];
      }
    if (j0 + 63 > i0 + 1024) {
#pragma unroll
      for (int jt = 0; jt < 4; ++jt)
#pragma unroll
        for (int r2 = 0; r2 < 4; ++r2) {
          int jl = jt * 16 + lhi * 4 + r2;
          if (j0 + jl > i0 + l15 + 1024) sv[jt][r2] = -1e30f;
        }
    }

    // ---- online softmax (log2 domain), defer-rescale ----
    float mx = sv[0][0];
#pragma unroll
    for (int jt = 0; jt < 4; ++jt)
#pragma unroll
      for (int r2 = 0; r2 < 4; ++r2) mx = fmaxf(mx, sv[jt][r2]);
    mx = fmaxf(mx, __shfl_xor(mx, 16, 64));
    mx = fmaxf(mx, __shfl_xor(mx, 32, 64));
    const bool resc = __any(mx > m_run + 8.0f);
    const float mn = resc ? fmaxf(m_run, mx) : m_run;
    float rs = 0.f;
#pragma unroll
    for (int jt = 0; jt < 4; ++jt)
#pragma unroll
      for (int r2 = 0; r2 < 4; ++r2) {
        float p = exp2f(sv[jt][r2] - mn);
        sv[jt][r2] = p;
        rs += p;
      }
    rs += __shfl_xor(rs, 16, 64);
    rs += __shfl_xor(rs, 32, 64);
    if (resc) {
      float corr = exp2f(m_run - mn);
      float c4[4];
#pragma unroll
      for (int r2 = 0; r2 < 4; ++r2) c4[r2] = __shfl(corr, lhi * 4 + r2, 64);
#pragma unroll
      for (int dt = 0; dt < 4; ++dt)
#pragma unroll
        for (int r2 = 0; r2 < 4; ++r2) accv[dt][r2] *= c4[r2];
      m_run = mn;
      l_run = l_run * corr + rs;
    } else {
      l_run += rs;
    }

    // ---- P -> LDS (row i = l15), then PV ----
#pragma unroll
    for (int jt = 0; jt < 4; ++jt) {
      bf16x4 pv;
      pv[0] = (__bf16)sv[jt][0]; pv[1] = (__bf16)sv[jt][1];
      pv[2] = (__bf16)sv[jt][2]; pv[3] = (__bf16)sv[jt][3];
      *(bf16x4*)(BPW + l15 * 72 + jt * 16 + lhi * 4) = pv;
    }
    bf16x8 ap0 = *(const bf16x8*)(BPW + l15 * 72 + lhi * 8);
    bf16x8 ap1 = *(const bf16x8*)(BPW + l15 * 72 + 32 + lhi * 8);
#pragma unroll
    for (int dt = 0; dt < 4; ++dt) {
      bf16x8 vf0 = ldsfrag(VtC, dt * 16 + l15, lhi);
      bf16x8 vf1 = ldsfrag(VtC, dt * 16 + l15, 4 + lhi);
      accv[dt] = mfma16(ap1, vf1, mfma16(ap0, vf0, accv[dt]));
    }
  }
#undef STAGE_KV

  // ---- epilogue: l_run lives at lane = row; fetch via shfl ----
  float inv4[4];
#pragma unroll
  for (int r2 = 0; r2 < 4; ++r2) inv4[r2] = 1.0f / __shfl(l_run, lhi * 4 + r2, 64);
#pragma unroll
  for (int dt = 0; dt < 4; ++dt)
#pragma unroll
    for (int r2 = 0; r2 < 4; ++r2) {
      int i = i0 + lhi * 4 + r2;
      float v = accv[dt][r2] * inv4[r2];
      vec[((size_t)(b * 1024 + i)) * 1024 + h * 64 + dt * 16 + l15] = (__bf16)v;
    }
}

// ---------------- layernorm ----------------
__global__ __launch_bounds__(256) void ln_kernel(const float* __restrict__ pre,
                                                 const float* __restrict__ gamma,
                                                 const float* __restrict__ beta,
                                                 float* __restrict__ out) {
  const int row = blockIdx.x;
  const int tid = threadIdx.x;
  const float4 v = ((const float4*)(pre + (size_t)row * 1024))[tid];
  float s = v.x + v.y + v.z + v.w;
  float s2 = v.x * v.x + v.y * v.y + v.z * v.z + v.w * v.w;
#pragma unroll
  for (int off = 1; off < 64; off <<= 1) {
    s += __shfl_xor(s, off, 64);
    s2 += __shfl_xor(s2, off, 64);
  }
  __shared__ float red[8];
  const int wid = tid >> 6;
  if ((tid & 63) == 0) { red[wid * 2] = s; red[wid * 2 + 1] = s2; }
  __syncthreads();
  s = red[0] + red[2] + red[4] + red[6];
  s2 = red[1] + red[3] + red[5] + red[7];
  float mu = s * (1.0f / 1024.0f);
  float var = s2 * (1.0f / 1024.0f) - mu * mu;
  float rstd = rsqrtf(var + 1e-5f);
  float4 g = ((const float4*)gamma)[tid];
  float4 be = ((const float4*)beta)[tid];
  float4 o;
  o.x = (v.x - mu) * rstd * g.x + be.x;
  o.y = (v.y - mu) * rstd * g.y + be.y;
  o.z = (v.z - mu) * rstd * g.z + be.z;
  o.w = (v.w - mu) * rstd * g.w + be.w;
  ((float4*)(out + (size_t)row * 1024))[tid] = o;
}

// ---------------- launcher ----------------
extern "C" void kernel_launch(void* const* d_in, const int* in_sizes, int n_in,
                              void* d_out, int out_size, void* d_ws, size_t ws_size,
                              hipStream_t stream) {
  const float* w = (const float*)d_in[0];
  const float* r = (const float*)d_in[1];
  const float* mem = (const float*)d_in[2];
  const float* qkv_w = (const float*)d_in[4];
  const float* r_w = (const float*)d_in[5];
  const float* o_w = (const float*)d_in[6];
  const float* r_r_bias = (const float*)d_in[7];
  const float* r_w_bias = (const float*)d_in[8];
  const float* gamma = (const float*)d_in[9];
  const float* beta = (const float*)d_in[10];
  float* out = (float*)d_out;

  char* ws = (char*)d_ws;
  const size_t MB = 1024 * 1024;
  __bf16* catB = (__bf16*)(ws + 0);
  __bf16* vT = (__bf16*)(ws + 0);
  float* pre = (float*)(ws + 0);
  __bf16* qkvwB = (__bf16*)(ws + 16 * MB);
  __bf16* rB = (__bf16*)(ws + 22 * MB);
  __bf16* rwB = (__bf16*)(ws + 26 * MB);
  __bf16* owB = (__bf16*)(ws + 28 * MB);
  __bf16* headsB = (__bf16*)(ws + 30 * MB);  // 48 MB
  __bf16* rkB = (__bf16*)(ws + 78 * MB);     // 4 MB
  __bf16* vecB = (__bf16*)(ws + 82 * MB);    // 8 MB
  float* ackbF = (float*)(ws + 90 * MB);     // 512 KB
  float* brkF = (float*)(ws + 91 * MB);      // 144 KB

  cast_cat<<<4096, 256, 0, stream>>>(mem, w, catB);
  cast_plain<<<1536, 256, 0, stream>>>(qkv_w, qkvwB);
  cast_plain<<<1024, 256, 0, stream>>>(r, rB);
  cast_plain<<<512, 256, 0, stream>>>(r_w, rwB);
  cast_plain<<<512, 256, 0, stream>>>(o_w, owB);

  gemm_bt<0><<<dim3(24, 64), 256, 0, stream>>>(catB, qkvwB, headsB, nullptr, nullptr,
                                               8192, 3072, 1024, 1);
  gemm_bt<0><<<dim3(8, 16), 256, 0, stream>>>(rB, rwB, rkB, nullptr, nullptr,
                                              2048, 1024, 1024, 0);

  vtrans_kernel<<<dim3(32, 16, 4), 256, 0, stream>>>(headsB, vT);
  ackb_kernel<<<512, 256, 0, stream>>>(headsB, r_w_bias, ackbF);
  brk_kernel<<<144, 256, 0, stream>>>(rkB, r_r_bias, brkF);

  attn_kernel<<<1024, 256, 0, stream>>>(headsB, rkB, vT, ackbF, brkF, vecB);

  gemm_bt<1><<<dim3(8, 32), 256, 0, stream>>>(vecB, owB, nullptr, pre, w,
                                              4096, 1024, 1024, 0);
  ln_kernel<<<4096, 256, 0, stream>>>(pre, gamma, beta, out);
}

// Round 5
// 316.373 us; speedup vs baseline: 1.1201x; 1.1201x over previous
//
#include <hip/hip_runtime.h>

typedef __attribute__((ext_vector_type(8))) __bf16 bf16x8;
typedef __attribute__((ext_vector_type(4))) __bf16 bf16x4;
typedef __attribute__((ext_vector_type(4))) float f32x4;
typedef __attribute__((ext_vector_type(16))) float f32x16;

#define SCALE_LOG2E 0.18033688011112042f  // 0.125 * log2(e)

__device__ __forceinline__ f32x4 mfma16(bf16x8 a, bf16x8 b, f32x4 c) {
  return __builtin_amdgcn_mfma_f32_16x16x32_bf16(a, b, c, 0, 0, 0);
}
__device__ __forceinline__ f32x16 mfma32(bf16x8 a, bf16x8 b, f32x16 c) {
  return __builtin_amdgcn_mfma_f32_32x32x16_bf16(a, b, c, 0, 0, 0);
}

__device__ __forceinline__ void gload_lds16(const void* g, void* l) {
  __builtin_amdgcn_global_load_lds(
      (__attribute__((address_space(1))) void*)(void*)g,
      (__attribute__((address_space(3))) void*)l, 16, 0, 0);
}

// read swizzled [row][64-elem] LDS tile: logical chunk lc (0..7) of row
__device__ __forceinline__ bf16x8 ldsfrag(const __bf16* base, int row, int lc) {
  return *(const bf16x8*)(base + row * 64 + ((lc ^ (row & 7)) << 3));
}

// ---------------- cast kernels ----------------

__global__ __launch_bounds__(256) void cast_plain(const float* __restrict__ in,
                                                  __bf16* __restrict__ out) {
  size_t t = (size_t)blockIdx.x * 256 + threadIdx.x;
  const float4* p = (const float4*)(in + t * 8);
  float4 a = p[0], b = p[1];
  bf16x8 v;
  v[0] = (__bf16)a.x; v[1] = (__bf16)a.y; v[2] = (__bf16)a.z; v[3] = (__bf16)a.w;
  v[4] = (__bf16)b.x; v[5] = (__bf16)b.y; v[6] = (__bf16)b.z; v[7] = (__bf16)b.w;
  *(bf16x8*)(out + t * 8) = v;
}

__global__ __launch_bounds__(256) void cast_cat(const float* __restrict__ mem,
                                                const float* __restrict__ w,
                                                __bf16* __restrict__ out) {
  size_t t = (size_t)blockIdx.x * 256 + threadIdx.x;
  size_t o = t * 8;
  int c = (int)(o & 1023);
  int row = (int)(o >> 10);
  int tt = row & 2047;
  int b = row >> 11;
  const float* src = (tt < 1024)
      ? (mem + ((size_t)(b * 1024 + tt) * 1024 + c))
      : (w + ((size_t)(b * 1024 + (tt - 1024)) * 1024 + c));
  float4 a = ((const float4*)src)[0], d = ((const float4*)src)[1];
  bf16x8 v;
  v[0] = (__bf16)a.x; v[1] = (__bf16)a.y; v[2] = (__bf16)a.z; v[3] = (__bf16)a.w;
  v[4] = (__bf16)d.x; v[5] = (__bf16)d.y; v[6] = (__bf16)d.z; v[7] = (__bf16)d.w;
  *(bf16x8*)(out + o) = v;
}

// ---------------- GEMM: C = A(MxK) * B(NxK)^T ----------------
template <int MODE>
__global__ __launch_bounds__(256, 2) void gemm_bt(const __bf16* __restrict__ A,
                                                  const __bf16* __restrict__ B,
                                                  __bf16* __restrict__ Cb,
                                                  float* __restrict__ Cf,
                                                  const float* __restrict__ Res,
                                                  int M, int N, int K, int skipq) {
  if (skipq && blockIdx.x < 8 && (blockIdx.y & 15) < 8) return;
  __shared__ __bf16 As[128 * 32];
  __shared__ __bf16 Bs[128 * 32];
  const int tid = threadIdx.x;
  const int wid = tid >> 6, lane = tid & 63;
  const int l15 = lane & 15, lhi = lane >> 4;
  const int wr = wid >> 1, wc = wid & 1;
  const size_t arow0 = (size_t)blockIdx.y * 128;
  const size_t brow0 = (size_t)blockIdx.x * 128;

  f32x4 acc[4][4] = {};

  const int c0 = tid, c1 = tid + 256;
  const int r0 = c0 >> 2, o0 = (c0 & 3) * 8;
  const int r1 = c1 >> 2, o1 = (c1 & 3) * 8;
  const __bf16* ga0 = A + (arow0 + r0) * K + o0;
  const __bf16* ga1 = A + (arow0 + r1) * K + o1;
  const __bf16* gb0 = B + (brow0 + r0) * K + o0;
  const __bf16* gb1 = B + (brow0 + r1) * K + o1;
  __bf16* la0 = As + wid * 512;
  __bf16* la1 = As + 2048 + wid * 512;
  __bf16* lb0 = Bs + wid * 512;
  __bf16* lb1 = Bs + 2048 + wid * 512;

  for (int k0 = 0; k0 < K; k0 += 32) {
    gload_lds16(ga0 + k0, la0);
    gload_lds16(ga1 + k0, la1);
    gload_lds16(gb0 + k0, lb0);
    gload_lds16(gb1 + k0, lb1);
    __syncthreads();
    bf16x8 af[4], bf[4];
#pragma unroll
    for (int m = 0; m < 4; ++m)
      af[m] = *(const bf16x8*)(As + (wr * 64 + m * 16 + l15) * 32 + lhi * 8);
#pragma unroll
    for (int n = 0; n < 4; ++n)
      bf[n] = *(const bf16x8*)(Bs + (wc * 64 + n * 16 + l15) * 32 + lhi * 8);
#pragma unroll
    for (int m = 0; m < 4; ++m)
#pragma unroll
      for (int n = 0; n < 4; ++n)
        acc[m][n] = mfma16(af[m], bf[n], acc[m][n]);
    __syncthreads();
  }

#pragma unroll
  for (int m = 0; m < 4; ++m)
#pragma unroll
    for (int n = 0; n < 4; ++n) {
      size_t row = arow0 + wr * 64 + m * 16 + lhi * 4;
      size_t col = brow0 + wc * 64 + n * 16 + l15;
#pragma unroll
      for (int j = 0; j < 4; ++j) {
        size_t idx = (row + j) * (size_t)N + col;
        float v = acc[m][n][j];
        if (MODE == 0) Cb[idx] = (__bf16)v;
        else Cf[idx] = v + Res[idx];
      }
    }
}

// ---------------- V transpose: vT[b][h][d][j] ----------------
__global__ __launch_bounds__(256) void vtrans_kernel(const __bf16* __restrict__ heads,
                                                     __bf16* __restrict__ vT) {
  __shared__ __bf16 T[64][66];
  const int j0 = blockIdx.x * 64;
  const int h = blockIdx.y, b = blockIdx.z;
  const int tid = threadIdx.x;
  {
    int jj = tid >> 2, dq = tid & 3;
    const __bf16* src = heads + ((size_t)(b * 2048 + j0 + jj)) * 3072 + 2048 + h * 64 + dq * 16;
    bf16x8 a = *(const bf16x8*)src;
    bf16x8 c = *(const bf16x8*)(src + 8);
#pragma unroll
    for (int e = 0; e < 8; ++e) { T[jj][dq * 16 + e] = a[e]; T[jj][dq * 16 + 8 + e] = c[e]; }
  }
  __syncthreads();
  {
    int d = tid >> 2, jq = tid & 3;
    bf16x8 o0, o1;
#pragma unroll
    for (int e = 0; e < 8; ++e) { o0[e] = T[jq * 16 + e][d]; o1[e] = T[jq * 16 + 8 + e][d]; }
    __bf16* dst = vT + ((size_t)((b * 16 + h) * 64 + d)) * 2048 + j0 + jq * 16;
    *(bf16x8*)dst = o0;
    *(bf16x8*)(dst + 8) = o1;
  }
}

// ---------------- bias-dot precomputes (scale = 0.125*log2e folded in) ----------------
__global__ __launch_bounds__(256) void ackb_kernel(const __bf16* __restrict__ heads,
                                                   const float* __restrict__ r_w_bias,
                                                   float* __restrict__ ackb) {
  int gid = blockIdx.x * 256 + threadIdx.x;  // 131072
  int j = gid & 2047, bh = gid >> 11, b = bh >> 4, h = bh & 15;
  const __bf16* kp = heads + ((size_t)(b * 2048 + j)) * 3072 + 1024 + h * 64;
  const float* bw = r_w_bias + h * 64;
  float s = 0.f;
#pragma unroll
  for (int o = 0; o < 8; ++o) {
    bf16x8 kv = *(const bf16x8*)(kp + o * 8);
#pragma unroll
    for (int e = 0; e < 8; ++e) s += (float)kv[e] * bw[o * 8 + e];
  }
  ackb[(size_t)bh * 2048 + j] = s * SCALE_LOG2E;
}

// brk[h][t] padded to 2304 per h (zeros past 2047)
__global__ __launch_bounds__(256) void brk_kernel(const __bf16* __restrict__ rk,
                                                  const float* __restrict__ r_r_bias,
                                                  float* __restrict__ brk) {
  int gid = blockIdx.x * 256 + threadIdx.x;  // 36864
  int t = gid % 2304, h = gid / 2304;
  float s = 0.f;
  if (t < 2048) {
    const __bf16* rp = rk + (size_t)t * 1024 + h * 64;
    const float* br = r_r_bias + h * 64;
#pragma unroll
    for (int o = 0; o < 8; ++o) {
      bf16x8 rv = *(const bf16x8*)(rp + o * 8);
#pragma unroll
      for (int e = 0; e < 8; ++e) s += (float)rv[e] * br[o * 8 + e];
    }
  }
  brk[(size_t)h * 2304 + t] = s * SCALE_LOG2E;
}

// ---------------- attention: 32x32 MFMA, QBLK=32/wave, KVBLK=64 ----------------
__global__ __launch_bounds__(256, 2) void attn_kernel(
    const __bf16* __restrict__ heads, const __bf16* __restrict__ rk,
    const __bf16* __restrict__ vT, const float* __restrict__ ackb,
    const float* __restrict__ brk, __bf16* __restrict__ vec) {
  __shared__ __bf16 Ks[64 * 64];     // 8 KB  K tile [j][d] swizzled
  __shared__ __bf16 Rst[192 * 64];   // 24 KB rk band window [r][d] swizzled
  __shared__ __bf16 BP[4][3200];     // 25.6 KB per-wave band(stride100)/P(stride88) union

  // balanced XCD-chunked decode: CU gets one long-bq and one complementary short-bq block
  const int lin = blockIdx.x;
  const int xcd = lin & 7, s = lin >> 3;     // 512 = 8 XCD * 64
  const int half = s >> 5, r5 = s & 31;
  const int bh = xcd * 8 + (r5 >> 3) + half * 4;
  const int bqr = r5 & 7;
  const int bq = half ? bqr : 7 - bqr;       // first half: longest first
  const int b = bh >> 4, h = bh & 15;
  const int base = bq << 7;                  // 128 q-rows per block

  const int tid = threadIdx.x;
  const int wid = tid >> 6, lane = tid & 63;
  const int il = lane & 31, hi5 = lane >> 5;
  const int i0 = base + wid * 32;

  const int srow8 = lane >> 3;
  const int sch = (lane & 7) ^ (srow8 & 7);

  // q fragments: lane supplies q[i0+il][kseg*16 + hi5*8 + e], pre-scaled
  bf16x8 qf[4];
  {
    const __bf16* qp =
        heads + ((size_t)(b * 2048 + 1024 + i0 + il)) * 3072 + h * 64 + hi5 * 8;
#pragma unroll
    for (int ks = 0; ks < 4; ++ks) {
      bf16x8 a = *(const bf16x8*)(qp + ks * 16);
      bf16x8 o;
#pragma unroll
      for (int e = 0; e < 8; ++e) o[e] = (__bf16)((float)a[e] * SCALE_LOG2E);
      qf[ks] = o;
    }
  }

  const float* ackbp = ackb + (size_t)bh * 2048;
  const float* brkp = brk + (size_t)h * 2304;
  const __bf16* vTp = vT + (size_t)bh * 64 * 2048;
  __bf16* Bw = BP[wid];

  float m_run = -1e30f, l_run = 0.f;
  f32x16 accv[2] = {};

  const int rkoff = 96 - wid * 32;
  const int jmaxb = min(2048, base + 1152);
  for (int j0 = 0; j0 < jmaxb; j0 += 64) {
    __syncthreads();  // B0: prior compute done
    {
      // K: 16 rows per wave
      const __bf16* kst = heads +
          ((size_t)(b * 2048 + j0 + wid * 16 + srow8)) * 3072 + 1024 + h * 64 + sch * 8;
      gload_lds16(kst, Ks + (wid * 16) * 64);
      gload_lds16(kst + (size_t)8 * 3072, Ks + (wid * 16 + 8) * 64);
      // rk window: 48 rows per wave (192 total), clamped
      const int rstart = j0 + 896 - base;
#pragma unroll
      for (int g = 0; g < 6; ++g) {
        int dr = wid * 48 + g * 8;
        int rg = min(rstart + dr + srow8, 2047);
        gload_lds16(rk + ((size_t)rg << 10) + h * 64 + sch * 8, Rst + dr * 64);
      }
    }
    __syncthreads();  // B1: staged data ready
    if (j0 >= i0 + 1056) continue;  // fully masked for this wave

    const int tbase = j0 + 992 - i0;  // rk row of band c=0 (>=0, mult of 16)

    // V fragments from global (L2), issued early
    bf16x8 vfr[4][2];
#pragma unroll
    for (int jc = 0; jc < 4; ++jc)
#pragma unroll
      for (int dt = 0; dt < 2; ++dt)
        vfr[jc][dt] = *(const bf16x8*)(vTp + (size_t)(dt * 32 + il) * 2048 +
                                       j0 + jc * 16 + hi5 * 8);

    __builtin_amdgcn_s_setprio(1);
    // ---- band: rows c, cols i; C-init = brk ----
#pragma unroll
    for (int ct = 0; ct < 3; ++ct) {
      f32x16 ci;
#pragma unroll
      for (int qd = 0; qd < 4; ++qd) {
        f32x4 b4 = *(const f32x4*)(brkp + tbase + ct * 32 + qd * 8 + hi5 * 4);
#pragma unroll
        for (int e = 0; e < 4; ++e) ci[qd * 4 + e] = b4[e];
      }
      const int ar = rkoff + ct * 32 + il;
#pragma unroll
      for (int ks = 0; ks < 4; ++ks)
        ci = mfma32(ldsfrag(Rst, ar, ks * 2 + hi5), qf[ks], ci);
#pragma unroll
      for (int qd = 0; qd < 4; ++qd) {
        union { unsigned u[2]; bf16x4 v; } pw;
        asm("v_cvt_pk_bf16_f32 %0, %1, %2"
            : "=v"(pw.u[0]) : "v"(ci[qd * 4 + 0]), "v"(ci[qd * 4 + 1]));
        asm("v_cvt_pk_bf16_f32 %0, %1, %2"
            : "=v"(pw.u[1]) : "v"(ci[qd * 4 + 2]), "v"(ci[qd * 4 + 3]));
        *(bf16x4*)(Bw + il * 100 + ct * 32 + qd * 8 + hi5 * 4) = pw.v;
      }
    }

    // ---- AC: S^T rows j, cols i; C-init = ackb ----
    f32x16 st[2];
#pragma unroll
    for (int jt = 0; jt < 2; ++jt) {
      f32x16 ci;
#pragma unroll
      for (int qd = 0; qd < 4; ++qd) {
        f32x4 a4 = *(const f32x4*)(ackbp + j0 + jt * 32 + qd * 8 + hi5 * 4);
#pragma unroll
        for (int e = 0; e < 4; ++e) ci[qd * 4 + e] = a4[e];
      }
#pragma unroll
      for (int ks = 0; ks < 4; ++ks)
        ci = mfma32(ldsfrag(Ks, jt * 32 + il, ks * 2 + hi5), qf[ks], ci);
      st[jt] = ci;
    }
    __builtin_amdgcn_s_setprio(0);

    // ---- assemble S = AC + shifted band ----
    float sv[2][16];
#pragma unroll
    for (int jt = 0; jt < 2; ++jt)
#pragma unroll
      for (int rg = 0; rg < 16; ++rg) {
        const int crow = (rg & 3) + 8 * (rg >> 2) + 4 * hi5;
        const int c = jt * 32 + crow + 31 - il;
        sv[jt][rg] = st[jt][rg] + (float)Bw[il * 100 + c];
      }
    if (j0 + 63 > i0 + 1024) {  // boundary: apply causal(+memlen) mask
#pragma unroll
      for (int jt = 0; jt < 2; ++jt)
#pragma unroll
        for (int rg = 0; rg < 16; ++rg) {
          const int crow = (rg & 3) + 8 * (rg >> 2) + 4 * hi5;
          if (j0 + jt * 32 + crow > i0 + il + 1024) sv[jt][rg] = -1e30f;
        }
    }

    // ---- online softmax (log2 domain), defer-rescale ----
    float mx = sv[0][0];
#pragma unroll
    for (int jt = 0; jt < 2; ++jt)
#pragma unroll
      for (int rg = 0; rg < 16; ++rg) mx = fmaxf(mx, sv[jt][rg]);
    mx = fmaxf(mx, __shfl_xor(mx, 32, 64));
    const bool resc = __any(mx > m_run + 8.0f);
    const float mn = resc ? fmaxf(m_run, mx) : m_run;
    float rs = 0.f;
#pragma unroll
    for (int jt = 0; jt < 2; ++jt)
#pragma unroll
      for (int rg = 0; rg < 16; ++rg) {
        float p = exp2f(sv[jt][rg] - mn);
        sv[jt][rg] = p;
        rs += p;
      }
    rs += __shfl_xor(rs, 32, 64);
    if (resc) {
      const float corr = exp2f(m_run - mn);
      m_run = mn;
      l_run = l_run * corr + rs;
      float c16[16];
#pragma unroll
      for (int rg = 0; rg < 16; ++rg) {
        const int crow = (rg & 3) + 8 * (rg >> 2) + 4 * hi5;
        c16[rg] = __shfl(corr, crow, 64);
      }
#pragma unroll
      for (int dt = 0; dt < 2; ++dt)
#pragma unroll
        for (int rg = 0; rg < 16; ++rg) accv[dt][rg] *= c16[rg];
    } else {
      l_run += rs;
    }

    // ---- P -> LDS [i][j] (stride 88, overwrites band region) ----
#pragma unroll
    for (int jt = 0; jt < 2; ++jt)
#pragma unroll
      for (int qd = 0; qd < 4; ++qd) {
        union { unsigned u[2]; bf16x4 v; } pw;
        asm("v_cvt_pk_bf16_f32 %0, %1, %2"
            : "=v"(pw.u[0]) : "v"(sv[jt][qd * 4 + 0]), "v"(sv[jt][qd * 4 + 1]));
        asm("v_cvt_pk_bf16_f32 %0, %1, %2"
            : "=v"(pw.u[1]) : "v"(sv[jt][qd * 4 + 2]), "v"(sv[jt][qd * 4 + 3]));
        *(bf16x4*)(Bw + il * 88 + jt * 32 + qd * 8 + hi5 * 4) = pw.v;
      }

    // ---- PV ----
    __builtin_amdgcn_s_setprio(1);
#pragma unroll
    for (int jc = 0; jc < 4; ++jc) {
      bf16x8 ap = *(const bf16x8*)(Bw + il * 88 + jc * 16 + hi5 * 8);
#pragma unroll
      for (int dt = 0; dt < 2; ++dt)
        accv[dt] = mfma32(ap, vfr[jc][dt], accv[dt]);
    }
    __builtin_amdgcn_s_setprio(0);
  }

  // ---- epilogue ----
  float linv[16];
#pragma unroll
  for (int rg = 0; rg < 16; ++rg) {
    const int crow = (rg & 3) + 8 * (rg >> 2) + 4 * hi5;
    linv[rg] = 1.0f / __shfl(l_run, crow, 64);
  }
#pragma unroll
  for (int dt = 0; dt < 2; ++dt)
#pragma unroll
    for (int rg = 0; rg < 16; ++rg) {
      const int crow = (rg & 3) + 8 * (rg >> 2) + 4 * hi5;
      vec[((size_t)(b * 1024 + i0 + crow)) * 1024 + h * 64 + dt * 32 + il] =
          (__bf16)(accv[dt][rg] * linv[rg]);
    }
}

// ---------------- layernorm ----------------
__global__ __launch_bounds__(256) void ln_kernel(const float* __restrict__ pre,
                                                 const float* __restrict__ gamma,
                                                 const float* __restrict__ beta,
                                                 float* __restrict__ out) {
  const int row = blockIdx.x;
  const int tid = threadIdx.x;
  const float4 v = ((const float4*)(pre + (size_t)row * 1024))[tid];
  float s = v.x + v.y + v.z + v.w;
  float s2 = v.x * v.x + v.y * v.y + v.z * v.z + v.w * v.w;
#pragma unroll
  for (int off = 1; off < 64; off <<= 1) {
    s += __shfl_xor(s, off, 64);
    s2 += __shfl_xor(s2, off, 64);
  }
  __shared__ float red[8];
  const int wid = tid >> 6;
  if ((tid & 63) == 0) { red[wid * 2] = s; red[wid * 2 + 1] = s2; }
  __syncthreads();
  s = red[0] + red[2] + red[4] + red[6];
  s2 = red[1] + red[3] + red[5] + red[7];
  float mu = s * (1.0f / 1024.0f);
  float var = s2 * (1.0f / 1024.0f) - mu * mu;
  float rstd = rsqrtf(var + 1e-5f);
  float4 g = ((const float4*)gamma)[tid];
  float4 be = ((const float4*)beta)[tid];
  float4 o;
  o.x = (v.x - mu) * rstd * g.x + be.x;
  o.y = (v.y - mu) * rstd * g.y + be.y;
  o.z = (v.z - mu) * rstd * g.z + be.z;
  o.w = (v.w - mu) * rstd * g.w + be.w;
  ((float4*)(out + (size_t)row * 1024))[tid] = o;
}

// ---------------- launcher ----------------
extern "C" void kernel_launch(void* const* d_in, const int* in_sizes, int n_in,
                              void* d_out, int out_size, void* d_ws, size_t ws_size,
                              hipStream_t stream) {
  const float* w = (const float*)d_in[0];
  const float* r = (const float*)d_in[1];
  const float* mem = (const float*)d_in[2];
  const float* qkv_w = (const float*)d_in[4];
  const float* r_w = (const float*)d_in[5];
  const float* o_w = (const float*)d_in[6];
  const float* r_r_bias = (const float*)d_in[7];
  const float* r_w_bias = (const float*)d_in[8];
  const float* gamma = (const float*)d_in[9];
  const float* beta = (const float*)d_in[10];
  float* out = (float*)d_out;

  char* ws = (char*)d_ws;
  const size_t MB = 1024 * 1024;
  __bf16* catB = (__bf16*)(ws + 0);
  __bf16* vT = (__bf16*)(ws + 0);        // reuses catB region after GEMM1
  float* pre = (float*)(ws + 0);
  __bf16* qkvwB = (__bf16*)(ws + 16 * MB);
  __bf16* rB = (__bf16*)(ws + 22 * MB);
  __bf16* rwB = (__bf16*)(ws + 26 * MB);
  __bf16* owB = (__bf16*)(ws + 28 * MB);
  __bf16* headsB = (__bf16*)(ws + 30 * MB);  // 48 MB
  __bf16* rkB = (__bf16*)(ws + 78 * MB);     // 4 MB
  __bf16* vecB = (__bf16*)(ws + 82 * MB);    // 8 MB
  float* ackbF = (float*)(ws + 90 * MB);     // 512 KB
  float* brkF = (float*)(ws + 91 * MB);      // 144 KB

  cast_cat<<<4096, 256, 0, stream>>>(mem, w, catB);
  cast_plain<<<1536, 256, 0, stream>>>(qkv_w, qkvwB);
  cast_plain<<<1024, 256, 0, stream>>>(r, rB);
  cast_plain<<<512, 256, 0, stream>>>(r_w, rwB);
  cast_plain<<<512, 256, 0, stream>>>(o_w, owB);

  gemm_bt<0><<<dim3(24, 64), 256, 0, stream>>>(catB, qkvwB, headsB, nullptr, nullptr,
                                               8192, 3072, 1024, 1);
  gemm_bt<0><<<dim3(8, 16), 256, 0, stream>>>(rB, rwB, rkB, nullptr, nullptr,
                                              2048, 1024, 1024, 0);

  vtrans_kernel<<<dim3(32, 16, 4), 256, 0, stream>>>(headsB, vT);
  ackb_kernel<<<512, 256, 0, stream>>>(headsB, r_w_bias, ackbF);
  brk_kernel<<<144, 256, 0, stream>>>(rkB, r_r_bias, brkF);

  attn_kernel<<<512, 256, 0, stream>>>(headsB, rkB, vT, ackbF, brkF, vecB);

  gemm_bt<1><<<dim3(8, 32), 256, 0, stream>>>(vecB, owB, nullptr, pre, w,
                                              4096, 1024, 1024, 0);
  ln_kernel<<<4096, 256, 0, stream>>>(pre, gamma, beta, out);
}